// Round 8
// baseline (304.783 us; speedup 1.0000x reference)
//
#include <hip/hip_runtime.h>
#include <math.h>

#define NEG_SLOPE 0.2f

typedef __attribute__((ext_vector_type(8))) short bf16x8;
typedef __attribute__((ext_vector_type(8))) unsigned short u16x8;
typedef __attribute__((ext_vector_type(4))) float f32x4;

__device__ __forceinline__ float lrelu(float t) { return t > 0.f ? t : NEG_SLOPE * t; }

__device__ __forceinline__ unsigned short f2bf(float f) {
    unsigned u = __float_as_uint(f);
    u = (u + 0x7FFFu + ((u >> 16) & 1u)) >> 16;  // RNE
    return (unsigned short)u;
}
__device__ __forceinline__ float bf2f(unsigned short s) {
    return __uint_as_float(((unsigned)s) << 16);
}

// K_a: zero deg + Wbt[col][k]=bf16(W1[k][col]) + w2col (one grid-stride kernel)
__global__ __launch_bounds__(256) void prep_kernel(
    const float* __restrict__ W1, const float* __restrict__ W2,
    unsigned short* __restrict__ Wbt, float* __restrict__ w2col,
    int* __restrict__ deg, int N)
{
    const int gid = blockIdx.x * 256 + threadIdx.x;
    const int gsz = gridDim.x * 256;
    for (int i = gid; i < N; i += gsz) deg[i] = 0;
    for (int i = gid; i < 256 * 128; i += gsz) {
        const int col = i >> 7, k = i & 127;
        Wbt[i] = f2bf(W1[k * 256 + col]);
    }
    if (gid < 256) w2col[gid] = W2[(size_t)gid * 64];
}

#define HIST_BLOCKS 512

// K_b: blocks [0,HIST_BLOCKS) do the dst histogram (grid-stride);
// blocks >= HIST_BLOCKS do the MFMA gemm h1 = bf16(x@W1) + fused logits.
__global__ __launch_bounds__(256) void gemmhist_kernel(
    const float* __restrict__ x, const unsigned short* __restrict__ Wbt,
    const float* __restrict__ a_src, const float* __restrict__ a_dst,
    const int* __restrict__ dsts, int* __restrict__ deg,
    unsigned short* __restrict__ h, float* __restrict__ als,
    float* __restrict__ ald, int N, int E)
{
    __shared__ unsigned short xs[16][136];
    __shared__ float hs[16][260];
    const int t = threadIdx.x;

    if (blockIdx.x < HIST_BLOCKS) {
        for (int e = blockIdx.x * 256 + t; e < E; e += HIST_BLOCKS * 256)
            atomicAdd(deg + dsts[e], 1);
        return;
    }

    const int lane = t & 63;
    const int wv = t >> 6;
    const int rb = (blockIdx.x - HIST_BLOCKS) * 16;
    {
        const int r = t >> 4, c0 = (t & 15) * 8;
        const int row = rb + r;
        float4 a = make_float4(0, 0, 0, 0), b4 = make_float4(0, 0, 0, 0);
        if (row < N) {
            a  = *(const float4*)(x + (size_t)row * 128 + c0);
            b4 = *(const float4*)(x + (size_t)row * 128 + c0 + 4);
        }
        u16x8 tv;
        tv[0] = f2bf(a.x);  tv[1] = f2bf(a.y);  tv[2] = f2bf(a.z);  tv[3] = f2bf(a.w);
        tv[4] = f2bf(b4.x); tv[5] = f2bf(b4.y); tv[6] = f2bf(b4.z); tv[7] = f2bf(b4.w);
        *(u16x8*)(&xs[r][c0]) = tv;
    }
    __syncthreads();

    const int arow = lane & 15;
    const int kc = lane >> 4;
    f32x4 acc[4] = {f32x4{0,0,0,0}, f32x4{0,0,0,0}, f32x4{0,0,0,0}, f32x4{0,0,0,0}};
#pragma unroll
    for (int kk = 0; kk < 4; ++kk) {
        const bf16x8 afrag = *(const bf16x8*)(&xs[arow][kk * 32 + kc * 8]);
#pragma unroll
        for (int ct = 0; ct < 4; ++ct) {
            const int col = wv * 64 + ct * 16 + arow;
            const bf16x8 bfrag = *(const bf16x8*)(Wbt + (size_t)col * 128 + kk * 32 + kc * 8);
            acc[ct] = __builtin_amdgcn_mfma_f32_16x16x32_bf16(afrag, bfrag, acc[ct], 0, 0, 0);
        }
    }
#pragma unroll
    for (int ct = 0; ct < 4; ++ct)
#pragma unroll
        for (int r = 0; r < 4; ++r)
            hs[kc * 4 + r][wv * 64 + ct * 16 + arow] = acc[ct][r];
    __syncthreads();

    {
        const int r2 = t >> 4, c2 = (t & 15) * 16;
        const int row2 = rb + r2;
        if (row2 < N) {
            u16x8 o0, o1;
#pragma unroll
            for (int i = 0; i < 8; ++i) {
                o0[i] = f2bf(hs[r2][c2 + i]);
                o1[i] = f2bf(hs[r2][c2 + 8 + i]);
            }
            *(u16x8*)(h + (size_t)row2 * 256 + c2) = o0;
            *(u16x8*)(h + (size_t)row2 * 256 + c2 + 8) = o1;
        }
    }
    {
        const int lr = lane >> 2;
        const int cbase = wv * 64 + (lane & 3) * 16;
        float sa = 0.f, da = 0.f;
#pragma unroll
        for (int i = 0; i < 16; ++i) {
            const float v = hs[lr][cbase + i];
            sa += v * a_src[cbase + i];
            da += v * a_dst[cbase + i];
        }
        sa += __shfl_xor(sa, 1); sa += __shfl_xor(sa, 2);
        da += __shfl_xor(da, 1); da += __shfl_xor(da, 2);
        if ((lane & 3) == 0) {
            const int row = rb + lr;
            if (row < N) {
                als[row * 4 + wv] = sa;
                ald[row * 4 + wv] = da;
            }
        }
    }
}

// K_c: one-kernel exclusive scan: each block redundantly sums its prefix
// directly from deg (L2-resident), then scans its own 256-chunk in LDS.
__global__ __launch_bounds__(256) void scan_kernel(
    const int* __restrict__ deg, int* __restrict__ rowptr,
    int* __restrict__ cursor, int N)
{
    __shared__ int red[256];
    __shared__ int sc[256];
    const int t = threadIdx.x;
    const int lim = blockIdx.x * 256;
    int psum = 0;
    for (int i = t; i < lim; i += 256) psum += deg[i];
    red[t] = psum;
    __syncthreads();
    for (int off = 128; off; off >>= 1) {
        if (t < off) red[t] += red[t + off];
        __syncthreads();
    }
    const int base = red[0];
    const int i = lim + t;
    const int v = (i < N) ? deg[i] : 0;
    sc[t] = v;
    __syncthreads();
    for (int off = 1; off < 256; off <<= 1) {
        int tmp = (t >= off) ? sc[t - off] : 0;
        __syncthreads();
        sc[t] += tmp;
        __syncthreads();
    }
    if (i < N) {
        const int ex = base + sc[t] - v;
        rowptr[i] = ex;
        cursor[i] = ex;
        if (i == N - 1) rowptr[N] = base + sc[t];
    }
}

// K_d: scatter src ids grouped by dst
__global__ __launch_bounds__(256) void scatter_kernel(
    const int* __restrict__ srcs, const int* __restrict__ dsts,
    int* __restrict__ cursor, int* __restrict__ ssrc, int E)
{
    const int e = blockIdx.x * 256 + threadIdx.x;
    if (e >= E) return;
    const int pos = atomicAdd(cursor + dsts[e], 1);
    ssrc[pos] = srcs[e];
}

// one wave per dst node; half-wave per edge, lane owns 8 channels.
// SGPR-base + 32-bit byte-offset gathers (s<<9 h-row, s<<4 als).
// No max subtraction. Self-edge inlined on half 0. Fused ELU + layer-2
// projection + layer-2 logits; {als2,h2} packed for node2.
__global__ __launch_bounds__(256) void node1_kernel(
    const int* __restrict__ rowptr, const int* __restrict__ ssrc,
    const float* __restrict__ als, const float* __restrict__ ald,
    const unsigned short* __restrict__ h, const float* __restrict__ b1,
    const float* __restrict__ w2col, const float* __restrict__ a_s2,
    const float* __restrict__ a_d2, float2* __restrict__ ah2,
    float* __restrict__ ald2, int N)
{
    const int wid = (blockIdx.x * 256 + threadIdx.x) >> 6;
    const int lane = threadIdx.x & 63;
    if (wid >= N) return;
    const int base = rowptr[wid];
    const int deg = rowptr[wid + 1] - base;
    const int hl = lane & 31;
    const int ch0 = hl * 8;
    const int hown = hl >> 3;
    const float ad_own = ald[wid * 4 + hown];
    const char* hb = (const char*)h + ch0 * 2;     // per-lane base
    const char* ab = (const char*)(als + hown);    // per-lane base

    float acc[8] = {};
    float den = 0.f;
    if ((lane >> 5) == 0) {  // self-loop edge
        const float alv = *(const float*)(ab + (((unsigned)wid) << 4));
        const float ee = __expf(lrelu(alv + ad_own));
        den = ee;
        const u16x8 hv = *(const u16x8*)(hb + (((unsigned)wid) << 9));
#pragma unroll
        for (int i = 0; i < 8; ++i) acc[i] = ee * bf2f(hv[i]);
    }
#pragma unroll 4
    for (int j = lane >> 5; j < deg; j += 2) {
        const unsigned s = (unsigned)ssrc[base + j];
        const float alv = *(const float*)(ab + (s << 4));
        const float ee = __expf(lrelu(alv + ad_own));
        den += ee;
        const u16x8 hv = *(const u16x8*)(hb + (s << 9));
#pragma unroll
        for (int i = 0; i < 8; ++i) acc[i] += ee * bf2f(hv[i]);
    }
    den += __shfl_xor(den, 32);
#pragma unroll
    for (int i = 0; i < 8; ++i) acc[i] += __shfl_xor(acc[i], 32);

    const float rd = 1.f / den;
    float bv[8], wvv[8];
    *(float4*)(bv)      = *(const float4*)(b1 + ch0);
    *(float4*)(bv + 4)  = *(const float4*)(b1 + ch0 + 4);
    *(float4*)(wvv)     = *(const float4*)(w2col + ch0);
    *(float4*)(wvv + 4) = *(const float4*)(w2col + ch0 + 4);
    float dot = 0.f;
#pragma unroll
    for (int i = 0; i < 8; ++i) {
        float v = acc[i] * rd + bv[i];
        v = v > 0.f ? v : expm1f(v);
        dot += v * wvv[i];
    }
    dot += __shfl_xor(dot, 16);
    dot += __shfl_xor(dot, 8);
    dot += __shfl_xor(dot, 4);
    dot += __shfl_xor(dot, 2);
    dot += __shfl_xor(dot, 1);
    if (lane == 0) {
        ah2[wid] = make_float2(dot * a_s2[0], dot);  // {als2, h2}
        ald2[wid] = dot * a_d2[0];
    }
}

// one wave per dst node: layer-2 plain exp-sum (no max) + sigmoid
__global__ __launch_bounds__(256) void node2_kernel(
    const int* __restrict__ rowptr, const int* __restrict__ ssrc,
    const float2* __restrict__ ah2, const float* __restrict__ ald2,
    const float* __restrict__ b2, float* __restrict__ out, int N)
{
    const int wid = (blockIdx.x * 256 + threadIdx.x) >> 6;
    const int lane = threadIdx.x & 63;
    if (wid >= N) return;
    const int base = rowptr[wid];
    const int deg = rowptr[wid + 1] - base;
    const float aldd = ald2[wid];
    const char* pb = (const char*)ah2;
    float den = 0.f, num = 0.f;
    if (lane == 0) {  // self-loop
        const float2 sh = *(const float2*)(pb + (((unsigned)wid) << 3));
        const float ee = __expf(lrelu(sh.x + aldd));
        den = ee;
        num = ee * sh.y;
    }
#pragma unroll 2
    for (int j = lane; j < deg; j += 64) {
        const unsigned s = (unsigned)ssrc[base + j];
        const float2 sh = *(const float2*)(pb + (s << 3));
        const float ee = __expf(lrelu(sh.x + aldd));
        den += ee;
        num += ee * sh.y;
    }
#pragma unroll
    for (int off = 32; off; off >>= 1) {
        den += __shfl_xor(den, off);
        num += __shfl_xor(num, off);
    }
    if (lane == 0) {
        const float v = num / den + b2[0];
        out[wid] = 1.f / (1.f + __expf(-v));
    }
}

extern "C" void kernel_launch(void* const* d_in, const int* in_sizes, int n_in,
                              void* d_out, int out_size, void* d_ws, size_t ws_size,
                              hipStream_t stream)
{
    const float* x   = (const float*)d_in[0];
    const int*   ei  = (const int*)d_in[1];
    const float* W1  = (const float*)d_in[2];
    const float* as1 = (const float*)d_in[3];
    const float* ad1 = (const float*)d_in[4];
    const float* b1  = (const float*)d_in[5];
    const float* W2  = (const float*)d_in[6];
    const float* as2 = (const float*)d_in[7];
    const float* ad2 = (const float*)d_in[8];
    const float* b2  = (const float*)d_in[9];

    const int N  = in_sizes[0] / 128;
    const int E  = in_sizes[1] / 2;
    const int nb = (N + 255) / 256;
    const int gb = (N + 15) / 16;
    const int* srcs = ei;
    const int* dsts = ei + E;
    float* out = (float*)d_out;

    char* w = (char*)d_ws;
    auto alloc = [&](size_t nbytes) -> void* {
        void* p = (void*)w;
        w += (nbytes + 255) & ~(size_t)255;
        return p;
    };
    unsigned short* h1 = (unsigned short*)alloc((size_t)N * 256 * 2);
    float* als1   = (float*)alloc((size_t)N * 4 * 4);
    float* ald1   = (float*)alloc((size_t)N * 4 * 4);
    int*   rowptr = (int*)alloc((size_t)(N + 1) * 4);
    int*   cursor = (int*)alloc((size_t)N * 4);
    int*   ssrc   = (int*)alloc((size_t)E * 4);
    float2* ah2   = (float2*)alloc((size_t)N * 8);
    float* ald2   = (float*)alloc((size_t)N * 4);
    int*   deg    = (int*)alloc((size_t)N * 4);
    unsigned short* Wbt = (unsigned short*)alloc((size_t)256 * 128 * 2);
    float* w2col  = (float*)alloc((size_t)256 * 4);

    prep_kernel<<<64, 256, 0, stream>>>(W1, W2, Wbt, w2col, deg, N);
    gemmhist_kernel<<<HIST_BLOCKS + gb, 256, 0, stream>>>(
        x, Wbt, as1, ad1, dsts, deg, h1, als1, ald1, N, E);
    scan_kernel<<<nb, 256, 0, stream>>>(deg, rowptr, cursor, N);
    scatter_kernel<<<(E + 255) / 256, 256, 0, stream>>>(srcs, dsts, cursor, ssrc, E);
    node1_kernel<<<(N + 3) / 4, 256, 0, stream>>>(rowptr, ssrc, als1, ald1, h1, b1,
                                                  w2col, as2, ad2, ah2, ald2, N);
    node2_kernel<<<(N + 3) / 4, 256, 0, stream>>>(rowptr, ssrc, ah2, ald2, b2, out, N);
}